// Round 1
// baseline (915.816 us; speedup 1.0000x reference)
//
#include <hip/hip_runtime.h>

#define DIN 128

// ---------------- degree / norm ----------------
__global__ __launch_bounds__(256) void deg_init_k(int* __restrict__ deg, int n) {
    int i = blockIdx.x * 256 + threadIdx.x;
    if (i < n) deg[i] = 1;  // self-loop
}

__global__ __launch_bounds__(256) void deg_count_k(const int* __restrict__ col, int e,
                                                   int* __restrict__ deg) {
    int i = blockIdx.x * 256 + threadIdx.x;
    if (i < e) atomicAdd(&deg[col[i]], 1);
}

__global__ __launch_bounds__(256) void dinv_k(const int* __restrict__ deg,
                                              float* __restrict__ dinv, int n) {
    int i = blockIdx.x * 256 + threadIdx.x;
    if (i < n) dinv[i] = rsqrtf((float)deg[i]);
}

// ---------------- 3-phase exclusive scan of deg -> col_ptr ----------------
// chunk = 1024 elements per block (256 threads x 4)
__global__ __launch_bounds__(256) void scan_p1(const int* __restrict__ deg, int n,
                                               int* __restrict__ bsum) {
    __shared__ int lds[256];
    int t = threadIdx.x;
    int base = blockIdx.x * 1024 + t * 4;
    int s = 0;
#pragma unroll
    for (int i = 0; i < 4; i++) {
        int idx = base + i;
        if (idx < n) s += deg[idx];
    }
    lds[t] = s;
    __syncthreads();
    for (int o = 128; o > 0; o >>= 1) {
        if (t < o) lds[t] += lds[t + o];
        __syncthreads();
    }
    if (t == 0) bsum[blockIdx.x] = lds[0];
}

// single block, nb <= 256
__global__ __launch_bounds__(256) void scan_p2(int* __restrict__ bsum, int nb) {
    __shared__ int lds[256];
    int t = threadIdx.x;
    int v = (t < nb) ? bsum[t] : 0;
    lds[t] = v;
    __syncthreads();
    for (int o = 1; o < 256; o <<= 1) {
        int tmp = 0;
        if (t >= o) tmp = lds[t - o];
        __syncthreads();
        lds[t] += tmp;
        __syncthreads();
    }
    if (t < nb) bsum[t] = lds[t] - v;  // exclusive
}

__global__ __launch_bounds__(256) void scan_p3(const int* __restrict__ deg, int n,
                                               const int* __restrict__ bsum,
                                               int* __restrict__ cptr,
                                               int* __restrict__ cur) {
    __shared__ int lds[256];
    int t = threadIdx.x;
    int base = blockIdx.x * 1024 + t * 4;
    int v[4];
    int s = 0;
#pragma unroll
    for (int i = 0; i < 4; i++) {
        int idx = base + i;
        v[i] = (idx < n) ? deg[idx] : 0;
        s += v[i];
    }
    lds[t] = s;
    __syncthreads();
    for (int o = 1; o < 256; o <<= 1) {
        int tmp = 0;
        if (t >= o) tmp = lds[t - o];
        __syncthreads();
        lds[t] += tmp;
        __syncthreads();
    }
    int off = bsum[blockIdx.x] + (lds[t] - s);  // exclusive within grid
#pragma unroll
    for (int i = 0; i < 4; i++) {
        int idx = base + i;
        if (idx < n) {
            cptr[idx] = off;
            cur[idx] = off;
            off += v[i];
            if (idx == n - 1) cptr[n] = off;
        }
    }
}

// ---------------- bucket fill (counting sort by dst) ----------------
__global__ __launch_bounds__(256) void fill_k(const int* __restrict__ row,
                                              const int* __restrict__ col, int E, int N,
                                              const float* __restrict__ dinv,
                                              int* __restrict__ cur,
                                              int* __restrict__ ssrc,
                                              float* __restrict__ snrm) {
    int gid = blockIdx.x * 256 + threadIdx.x;
    int total = E + N;
    if (gid >= total) return;
    int s, d;
    if (gid < E) {
        s = row[gid];
        d = col[gid];
    } else {
        s = d = gid - E;  // self-loop
    }
    int p = atomicAdd(&cur[d], 1);
    ssrc[p] = s;
    snrm[p] = dinv[s] * dinv[d];
}

// ---------------- fp32 GEMM: C[n][DOUT] = A[n][128] @ W[128][DOUT] ----------------
// 64-row tile per block, K in 2 phases of 64 (LDS: 32KB W + 16KB A for DOUT=128)
template <int DOUT>
__global__ __launch_bounds__(256) void gemm_k(const float* __restrict__ A,
                                              const float* __restrict__ W,
                                              float* __restrict__ C, int n) {
    constexpr int CG = DOUT / 4;   // col groups (32 or 16)
    constexpr int RG = 256 / CG;   // row groups (8 or 16)
    constexpr int RPT = 64 / RG;   // rows per thread (8 or 4)
    constexpr int KT = 64;
    __shared__ float ldsW[KT * DOUT];
    __shared__ float ldsX[64 * KT];
    int tid = threadIdx.x;
    int rowbase = blockIdx.x * 64;
    int cg = tid % CG, rg = tid / CG;
    int c0 = cg * 4;
    int r0 = rg * RPT;
    float acc[RPT][4];
#pragma unroll
    for (int i = 0; i < RPT; i++)
#pragma unroll
        for (int j = 0; j < 4; j++) acc[i][j] = 0.f;

    for (int kp = 0; kp < 2; kp++) {
        const float4* Wg = (const float4*)(W + kp * KT * DOUT);
        float4* Wl = (float4*)ldsW;
        for (int i = tid; i < KT * DOUT / 4; i += 256) Wl[i] = Wg[i];
        for (int i = tid; i < 64 * KT / 4; i += 256) {
            int r = i >> 4;
            int kq = i & 15;
            int gr = rowbase + r;
            float4 v = make_float4(0.f, 0.f, 0.f, 0.f);
            if (gr < n) v = *(const float4*)(A + (size_t)gr * DIN + kp * KT + kq * 4);
            *(float4*)(ldsX + r * KT + kq * 4) = v;
        }
        __syncthreads();
#pragma unroll 4
        for (int k = 0; k < KT; k++) {
            float4 b = *(const float4*)(ldsW + k * DOUT + c0);
#pragma unroll
            for (int i = 0; i < RPT; i++) {
                float a = ldsX[(r0 + i) * KT + k];
                acc[i][0] += a * b.x;
                acc[i][1] += a * b.y;
                acc[i][2] += a * b.z;
                acc[i][3] += a * b.w;
            }
        }
        __syncthreads();
    }
#pragma unroll
    for (int i = 0; i < RPT; i++) {
        int gr = rowbase + r0 + i;
        if (gr < n)
            *(float4*)(C + (size_t)gr * DOUT + c0) =
                make_float4(acc[i][0], acc[i][1], acc[i][2], acc[i][3]);
    }
}

// ---------------- gather-aggregate: out[d] = bias + sum norm*xw[src] ----------------
// one wave per destination node
template <int D, bool RELU>
__global__ __launch_bounds__(256) void aggregate_k(const float* __restrict__ xw,
                                                   const int* __restrict__ ptr,
                                                   const int* __restrict__ src,
                                                   const float* __restrict__ nrm,
                                                   const float* __restrict__ bias,
                                                   float* __restrict__ out, int n) {
    int lane = threadIdx.x & 63;
    int node = blockIdx.x * 4 + (threadIdx.x >> 6);
    if (node >= n) return;
    int e0 = ptr[node], e1 = ptr[node + 1];
    if (D == 128) {
        float ax = 0.f, ay = 0.f;
        for (int e = e0; e < e1; e++) {
            int s = src[e];
            float w = nrm[e];
            float2 v = *(const float2*)(xw + (size_t)s * 128 + lane * 2);
            ax += w * v.x;
            ay += w * v.y;
        }
        float2 bb = *(const float2*)(bias + lane * 2);
        ax += bb.x;
        ay += bb.y;
        if (RELU) {
            ax = fmaxf(ax, 0.f);
            ay = fmaxf(ay, 0.f);
        }
        *(float2*)(out + (size_t)node * 128 + lane * 2) = make_float2(ax, ay);
    } else {
        float a = 0.f;
        for (int e = e0; e < e1; e++) {
            int s = src[e];
            a += nrm[e] * xw[(size_t)s * 64 + lane];
        }
        a += bias[lane];
        if (RELU) a = fmaxf(a, 0.f);
        out[(size_t)node * 64 + lane] = a;
    }
}

extern "C" void kernel_launch(void* const* d_in, const int* in_sizes, int n_in,
                              void* d_out, int out_size, void* d_ws, size_t ws_size,
                              hipStream_t stream) {
    const float* x = (const float*)d_in[0];
    const int* ei = (const int*)d_in[1];
    const float* W1 = (const float*)d_in[2];
    const float* b1 = (const float*)d_in[3];
    const float* W2 = (const float*)d_in[4];
    const float* b2 = (const float*)d_in[5];
    const float* W3 = (const float*)d_in[6];
    const float* b3 = (const float*)d_in[7];
    float* out = (float*)d_out;
    int N = in_sizes[0] / 128;
    int E = in_sizes[1] / 2;
    const int* row = ei;
    const int* col = ei + E;
    int T = E + N;

    char* w = (char*)d_ws;
    size_t off = 0;
    auto alloc = [&](size_t bytes) -> void* {
        void* p = w + off;
        off = (off + bytes + 511) & ~(size_t)511;
        return p;
    };
    float* bufA = (float*)alloc((size_t)N * 128 * 4);
    float* bufB = (float*)alloc((size_t)N * 128 * 4);
    int* deg = (int*)alloc((size_t)N * 4);
    float* dinv = (float*)alloc((size_t)N * 4);
    int* cptr = (int*)alloc((size_t)(N + 1) * 4);
    int* cur = (int*)alloc((size_t)N * 4);
    int* ssrc = (int*)alloc((size_t)T * 4);
    float* snrm = (float*)alloc((size_t)T * 4);
    int* bsum = (int*)alloc(4096);

    int nb = (N + 1023) / 1024;  // 98 for N=100000, must be <=256
    deg_init_k<<<(N + 255) / 256, 256, 0, stream>>>(deg, N);
    deg_count_k<<<(E + 255) / 256, 256, 0, stream>>>(col, E, deg);
    dinv_k<<<(N + 255) / 256, 256, 0, stream>>>(deg, dinv, N);
    scan_p1<<<nb, 256, 0, stream>>>(deg, N, bsum);
    scan_p2<<<1, 256, 0, stream>>>(bsum, nb);
    scan_p3<<<nb, 256, 0, stream>>>(deg, N, bsum, cptr, cur);
    fill_k<<<(T + 255) / 256, 256, 0, stream>>>(row, col, E, N, dinv, cur, ssrc, snrm);

    int gb = (N + 63) / 64;
    int ab = (N + 3) / 4;
    // layer 1: x -> xw (bufB) -> h1 (bufA)
    gemm_k<128><<<gb, 256, 0, stream>>>(x, W1, bufB, N);
    aggregate_k<128, true><<<ab, 256, 0, stream>>>(bufB, cptr, ssrc, snrm, b1, bufA, N);
    // layer 2: h1 -> xw (bufB) -> h2 (bufA)
    gemm_k<128><<<gb, 256, 0, stream>>>(bufA, W2, bufB, N);
    aggregate_k<128, true><<<ab, 256, 0, stream>>>(bufB, cptr, ssrc, snrm, b2, bufA, N);
    // layer 3: h2 -> xw (bufB, 64-wide) -> out
    gemm_k<64><<<gb, 256, 0, stream>>>(bufA, W3, bufB, N);
    aggregate_k<64, false><<<ab, 256, 0, stream>>>(bufB, cptr, ssrc, snrm, b3, out, N);
}

// Round 2
// 702.556 us; speedup vs baseline: 1.3035x; 1.3035x over previous
//
#include <hip/hip_runtime.h>

#define DIN 128

// ---------------- degree / norm ----------------
__global__ __launch_bounds__(256) void deg_init_k(int* __restrict__ deg, int n) {
    int i = blockIdx.x * 256 + threadIdx.x;
    if (i < n) deg[i] = 1;  // self-loop
}

__global__ __launch_bounds__(256) void deg_count_k(const int* __restrict__ col, int e,
                                                   int* __restrict__ deg) {
    int i = blockIdx.x * 256 + threadIdx.x;
    if (i < e) atomicAdd(&deg[col[i]], 1);
}

__global__ __launch_bounds__(256) void dinv_k(const int* __restrict__ deg,
                                              float* __restrict__ dinv, int n) {
    int i = blockIdx.x * 256 + threadIdx.x;
    if (i < n) dinv[i] = rsqrtf((float)deg[i]);
}

// ---------------- 3-phase exclusive scan of deg -> col_ptr ----------------
__global__ __launch_bounds__(256) void scan_p1(const int* __restrict__ deg, int n,
                                               int* __restrict__ bsum) {
    __shared__ int lds[256];
    int t = threadIdx.x;
    int base = blockIdx.x * 1024 + t * 4;
    int s = 0;
#pragma unroll
    for (int i = 0; i < 4; i++) {
        int idx = base + i;
        if (idx < n) s += deg[idx];
    }
    lds[t] = s;
    __syncthreads();
    for (int o = 128; o > 0; o >>= 1) {
        if (t < o) lds[t] += lds[t + o];
        __syncthreads();
    }
    if (t == 0) bsum[blockIdx.x] = lds[0];
}

__global__ __launch_bounds__(256) void scan_p2(int* __restrict__ bsum, int nb) {
    __shared__ int lds[256];
    int t = threadIdx.x;
    int v = (t < nb) ? bsum[t] : 0;
    lds[t] = v;
    __syncthreads();
    for (int o = 1; o < 256; o <<= 1) {
        int tmp = 0;
        if (t >= o) tmp = lds[t - o];
        __syncthreads();
        lds[t] += tmp;
        __syncthreads();
    }
    if (t < nb) bsum[t] = lds[t] - v;  // exclusive
}

__global__ __launch_bounds__(256) void scan_p3(const int* __restrict__ deg, int n,
                                               const int* __restrict__ bsum,
                                               int* __restrict__ cptr,
                                               int* __restrict__ cur) {
    __shared__ int lds[256];
    int t = threadIdx.x;
    int base = blockIdx.x * 1024 + t * 4;
    int v[4];
    int s = 0;
#pragma unroll
    for (int i = 0; i < 4; i++) {
        int idx = base + i;
        v[i] = (idx < n) ? deg[idx] : 0;
        s += v[i];
    }
    lds[t] = s;
    __syncthreads();
    for (int o = 1; o < 256; o <<= 1) {
        int tmp = 0;
        if (t >= o) tmp = lds[t - o];
        __syncthreads();
        lds[t] += tmp;
        __syncthreads();
    }
    int off = bsum[blockIdx.x] + (lds[t] - s);
#pragma unroll
    for (int i = 0; i < 4; i++) {
        int idx = base + i;
        if (idx < n) {
            cptr[idx] = off;
            cur[idx] = off;
            off += v[i];
            if (idx == n - 1) cptr[n] = off;
        }
    }
}

// ---------------- bucket fill: packed (src, norm) per slot ----------------
__global__ __launch_bounds__(256) void fill_k(const int* __restrict__ row,
                                              const int* __restrict__ col, int E, int N,
                                              const float* __restrict__ dinv,
                                              int* __restrict__ cur,
                                              int2* __restrict__ meta) {
    int gid = blockIdx.x * 256 + threadIdx.x;
    int total = E + N;
    if (gid >= total) return;
    int s, d;
    if (gid < E) {
        s = row[gid];
        d = col[gid];
    } else {
        s = d = gid - E;  // self-loop
    }
    int p = atomicAdd(&cur[d], 1);
    float w = dinv[s] * dinv[d];
    meta[p] = make_int2(s, __float_as_int(w));
}

// ---------------- fp32 GEMM: C[n][DOUT] = A[n][128] @ W[128][DOUT] ----------------
// 64-row tile per block; k-major (transposed) X in LDS so the inner loop is
// pure ds_read_b128: per k, 2(or 1) b128 A-frag reads + 1 b128 W read + 32(16) FMA.
template <int DOUT>
__global__ __launch_bounds__(256) void gemm_k(const float* __restrict__ A,
                                              const float* __restrict__ W,
                                              float* __restrict__ C, int n) {
    constexpr int KT = 32;
    constexpr int RPT = (DOUT == 128) ? 8 : 4;  // rows per thread
    constexpr int CG = DOUT / 4;                // col groups
    constexpr int XP = 132;                     // padded k-major row stride (16B-aligned, 2-way banks)
    __shared__ float ldsW[KT * DOUT];
    __shared__ float ldsX[KT * XP];
    int tid = threadIdx.x;
    int rowbase = blockIdx.x * 64;
    int c0 = (tid % CG) * 4;
    int r0 = (tid / CG) * RPT;
    float acc[RPT][4];
#pragma unroll
    for (int i = 0; i < RPT; i++)
#pragma unroll
        for (int j = 0; j < 4; j++) acc[i][j] = 0.f;

    for (int kp = 0; kp < 128 / KT; kp++) {
        // stage W tile (row-major, straight copy)
        const float4* Wg = (const float4*)(W + kp * KT * DOUT);
#pragma unroll
        for (int i = tid; i < KT * DOUT / 4; i += 256) ((float4*)ldsW)[i] = Wg[i];
        // stage X tile transposed: ldsX[k][r]
#pragma unroll
        for (int i = tid; i < 64 * KT / 4; i += 256) {
            int r = i & 63;
            int q = i >> 6;  // k-quad within phase
            int gr = rowbase + r;
            float4 v = make_float4(0.f, 0.f, 0.f, 0.f);
            if (gr < n) v = *(const float4*)(A + (size_t)gr * DIN + kp * KT + q * 4);
            ldsX[(q * 4 + 0) * XP + r] = v.x;
            ldsX[(q * 4 + 1) * XP + r] = v.y;
            ldsX[(q * 4 + 2) * XP + r] = v.z;
            ldsX[(q * 4 + 3) * XP + r] = v.w;
        }
        __syncthreads();
#pragma unroll 8
        for (int k = 0; k < KT; k++) {
            float4 b = *(const float4*)(ldsW + k * DOUT + c0);
            float4 a0 = *(const float4*)(ldsX + k * XP + r0);
            float av[RPT];
            av[0] = a0.x; av[1] = a0.y; av[2] = a0.z; av[3] = a0.w;
            if (RPT == 8) {
                float4 a1 = *(const float4*)(ldsX + k * XP + r0 + 4);
                av[4] = a1.x; av[5] = a1.y; av[6] = a1.z; av[7] = a1.w;
            }
#pragma unroll
            for (int i = 0; i < RPT; i++) {
                acc[i][0] = fmaf(av[i], b.x, acc[i][0]);
                acc[i][1] = fmaf(av[i], b.y, acc[i][1]);
                acc[i][2] = fmaf(av[i], b.z, acc[i][2]);
                acc[i][3] = fmaf(av[i], b.w, acc[i][3]);
            }
        }
        __syncthreads();
    }
#pragma unroll
    for (int i = 0; i < RPT; i++) {
        int gr = rowbase + r0 + i;
        if (gr < n)
            *(float4*)(C + (size_t)gr * DOUT + c0) =
                make_float4(acc[i][0], acc[i][1], acc[i][2], acc[i][3]);
    }
}

// ---------------- gather-aggregate: out[d] = bias + sum norm*xw[src] ----------------
// one wave per destination node; edge loop unrolled x4 for memory-level parallelism
template <int D, bool RELU>
__global__ __launch_bounds__(256) void aggregate_k(const float* __restrict__ xw,
                                                   const int* __restrict__ ptr,
                                                   const int2* __restrict__ meta,
                                                   const float* __restrict__ bias,
                                                   float* __restrict__ out, int n) {
    int lane = threadIdx.x & 63;
    int node = blockIdx.x * 4 + (threadIdx.x >> 6);
    if (node >= n) return;
    int e0 = ptr[node], e1 = ptr[node + 1];
    if (D == 128) {
        float ax = 0.f, ay = 0.f;
        int e = e0;
        for (; e + 4 <= e1; e += 4) {
            int2 m0 = meta[e], m1 = meta[e + 1], m2 = meta[e + 2], m3 = meta[e + 3];
            float2 v0 = *(const float2*)(xw + (size_t)m0.x * 128 + lane * 2);
            float2 v1 = *(const float2*)(xw + (size_t)m1.x * 128 + lane * 2);
            float2 v2 = *(const float2*)(xw + (size_t)m2.x * 128 + lane * 2);
            float2 v3 = *(const float2*)(xw + (size_t)m3.x * 128 + lane * 2);
            float w0 = __int_as_float(m0.y), w1 = __int_as_float(m1.y);
            float w2 = __int_as_float(m2.y), w3 = __int_as_float(m3.y);
            ax = fmaf(w0, v0.x, ax); ay = fmaf(w0, v0.y, ay);
            ax = fmaf(w1, v1.x, ax); ay = fmaf(w1, v1.y, ay);
            ax = fmaf(w2, v2.x, ax); ay = fmaf(w2, v2.y, ay);
            ax = fmaf(w3, v3.x, ax); ay = fmaf(w3, v3.y, ay);
        }
        for (; e < e1; e++) {
            int2 m = meta[e];
            float w = __int_as_float(m.y);
            float2 v = *(const float2*)(xw + (size_t)m.x * 128 + lane * 2);
            ax = fmaf(w, v.x, ax); ay = fmaf(w, v.y, ay);
        }
        float2 bb = *(const float2*)(bias + lane * 2);
        ax += bb.x; ay += bb.y;
        if (RELU) { ax = fmaxf(ax, 0.f); ay = fmaxf(ay, 0.f); }
        *(float2*)(out + (size_t)node * 128 + lane * 2) = make_float2(ax, ay);
    } else {
        float a = 0.f;
        int e = e0;
        for (; e + 4 <= e1; e += 4) {
            int2 m0 = meta[e], m1 = meta[e + 1], m2 = meta[e + 2], m3 = meta[e + 3];
            float v0 = xw[(size_t)m0.x * 64 + lane];
            float v1 = xw[(size_t)m1.x * 64 + lane];
            float v2 = xw[(size_t)m2.x * 64 + lane];
            float v3 = xw[(size_t)m3.x * 64 + lane];
            a = fmaf(__int_as_float(m0.y), v0, a);
            a = fmaf(__int_as_float(m1.y), v1, a);
            a = fmaf(__int_as_float(m2.y), v2, a);
            a = fmaf(__int_as_float(m3.y), v3, a);
        }
        for (; e < e1; e++) {
            int2 m = meta[e];
            a = fmaf(__int_as_float(m.y), xw[(size_t)m.x * 64 + lane], a);
        }
        a += bias[lane];
        if (RELU) a = fmaxf(a, 0.f);
        out[(size_t)node * 64 + lane] = a;
    }
}

extern "C" void kernel_launch(void* const* d_in, const int* in_sizes, int n_in,
                              void* d_out, int out_size, void* d_ws, size_t ws_size,
                              hipStream_t stream) {
    const float* x = (const float*)d_in[0];
    const int* ei = (const int*)d_in[1];
    const float* W1 = (const float*)d_in[2];
    const float* b1 = (const float*)d_in[3];
    const float* W2 = (const float*)d_in[4];
    const float* b2 = (const float*)d_in[5];
    const float* W3 = (const float*)d_in[6];
    const float* b3 = (const float*)d_in[7];
    float* out = (float*)d_out;
    int N = in_sizes[0] / 128;
    int E = in_sizes[1] / 2;
    const int* row = ei;
    const int* col = ei + E;
    int T = E + N;

    char* w = (char*)d_ws;
    size_t off = 0;
    auto alloc = [&](size_t bytes) -> void* {
        void* p = w + off;
        off = (off + bytes + 511) & ~(size_t)511;
        return p;
    };
    float* bufA = (float*)alloc((size_t)N * 128 * 4);
    float* bufB = (float*)alloc((size_t)N * 128 * 4);
    int* deg = (int*)alloc((size_t)N * 4);
    float* dinv = (float*)alloc((size_t)N * 4);
    int* cptr = (int*)alloc((size_t)(N + 1) * 4);
    int* cur = (int*)alloc((size_t)N * 4);
    int2* meta = (int2*)alloc((size_t)T * 8);
    int* bsum = (int*)alloc(4096);

    int nb = (N + 1023) / 1024;
    deg_init_k<<<(N + 255) / 256, 256, 0, stream>>>(deg, N);
    deg_count_k<<<(E + 255) / 256, 256, 0, stream>>>(col, E, deg);
    dinv_k<<<(N + 255) / 256, 256, 0, stream>>>(deg, dinv, N);
    scan_p1<<<nb, 256, 0, stream>>>(deg, N, bsum);
    scan_p2<<<1, 256, 0, stream>>>(bsum, nb);
    scan_p3<<<nb, 256, 0, stream>>>(deg, N, bsum, cptr, cur);
    fill_k<<<(T + 255) / 256, 256, 0, stream>>>(row, col, E, N, dinv, cur, meta);

    int gb = (N + 63) / 64;
    int ab = (N + 3) / 4;
    gemm_k<128><<<gb, 256, 0, stream>>>(x, W1, bufB, N);
    aggregate_k<128, true><<<ab, 256, 0, stream>>>(bufB, cptr, meta, b1, bufA, N);
    gemm_k<128><<<gb, 256, 0, stream>>>(bufA, W2, bufB, N);
    aggregate_k<128, true><<<ab, 256, 0, stream>>>(bufB, cptr, meta, b2, bufA, N);
    gemm_k<64><<<gb, 256, 0, stream>>>(bufA, W3, bufB, N);
    aggregate_k<64, false><<<ab, 256, 0, stream>>>(bufB, cptr, meta, b3, out, N);
}

// Round 4
// 695.739 us; speedup vs baseline: 1.3163x; 1.0098x over previous
//
#include <hip/hip_runtime.h>

#define DIN 128

// ---------------- degree / norm ----------------
__global__ __launch_bounds__(256) void deg_init_k(int* __restrict__ deg, int n) {
    int i = blockIdx.x * 256 + threadIdx.x;
    if (i < n) deg[i] = 1;  // self-loop
}

__global__ __launch_bounds__(256) void deg_count_k(const int* __restrict__ col, int e,
                                                   int* __restrict__ deg) {
    int i = blockIdx.x * 256 + threadIdx.x;
    if (i < e) atomicAdd(&deg[col[i]], 1);
}

__global__ __launch_bounds__(256) void dinv_k(const int* __restrict__ deg,
                                              float* __restrict__ dinv, int n) {
    int i = blockIdx.x * 256 + threadIdx.x;
    if (i < n) dinv[i] = rsqrtf((float)deg[i]);
}

// ---------------- 3-phase exclusive scan of deg -> col_ptr ----------------
__global__ __launch_bounds__(256) void scan_p1(const int* __restrict__ deg, int n,
                                               int* __restrict__ bsum) {
    __shared__ int lds[256];
    int t = threadIdx.x;
    int base = blockIdx.x * 1024 + t * 4;
    int s = 0;
#pragma unroll
    for (int i = 0; i < 4; i++) {
        int idx = base + i;
        if (idx < n) s += deg[idx];
    }
    lds[t] = s;
    __syncthreads();
    for (int o = 128; o > 0; o >>= 1) {
        if (t < o) lds[t] += lds[t + o];
        __syncthreads();
    }
    if (t == 0) bsum[blockIdx.x] = lds[0];
}

__global__ __launch_bounds__(256) void scan_p2(int* __restrict__ bsum, int nb) {
    __shared__ int lds[256];
    int t = threadIdx.x;
    int v = (t < nb) ? bsum[t] : 0;
    lds[t] = v;
    __syncthreads();
    for (int o = 1; o < 256; o <<= 1) {
        int tmp = 0;
        if (t >= o) tmp = lds[t - o];
        __syncthreads();
        lds[t] += tmp;
        __syncthreads();
    }
    if (t < nb) bsum[t] = lds[t] - v;  // exclusive
}

__global__ __launch_bounds__(256) void scan_p3(const int* __restrict__ deg, int n,
                                               const int* __restrict__ bsum,
                                               int* __restrict__ cptr,
                                               int* __restrict__ cur) {
    __shared__ int lds[256];
    int t = threadIdx.x;
    int base = blockIdx.x * 1024 + t * 4;
    int v[4];
    int s = 0;
#pragma unroll
    for (int i = 0; i < 4; i++) {
        int idx = base + i;
        v[i] = (idx < n) ? deg[idx] : 0;
        s += v[i];
    }
    lds[t] = s;
    __syncthreads();
    for (int o = 1; o < 256; o <<= 1) {
        int tmp = 0;
        if (t >= o) tmp = lds[t - o];
        __syncthreads();
        lds[t] += tmp;
        __syncthreads();
    }
    int off = bsum[blockIdx.x] + (lds[t] - s);
#pragma unroll
    for (int i = 0; i < 4; i++) {
        int idx = base + i;
        if (idx < n) {
            cptr[idx] = off;
            cur[idx] = off;
            off += v[i];
            if (idx == n - 1) cptr[n] = off;
        }
    }
}

// ---------------- bucket fill: packed (src, norm) per slot ----------------
__global__ __launch_bounds__(256) void fill_k(const int* __restrict__ row,
                                              const int* __restrict__ col, int E, int N,
                                              const float* __restrict__ dinv,
                                              int* __restrict__ cur,
                                              int2* __restrict__ meta) {
    int gid = blockIdx.x * 256 + threadIdx.x;
    int total = E + N;
    if (gid >= total) return;
    int s, d;
    if (gid < E) {
        s = row[gid];
        d = col[gid];
    } else {
        s = d = gid - E;  // self-loop
    }
    int p = atomicAdd(&cur[d], 1);
    float w = dinv[s] * dinv[d];
    meta[p] = make_int2(s, __float_as_int(w));
}

// ---------------- fp32 GEMM: C[n][DOUT] = A[n][128] @ W[128][DOUT] ----------------
// 128-row tile per block, k-major X in LDS. Per thread-k: 1 float4 W read +
// RPT/4 float4 X reads (broadcast) + RPT*4 FMA. RPT=16 for DOUT=128.
template <int DOUT>
__global__ __launch_bounds__(256) void gemm_k(const float* __restrict__ A,
                                              const float* __restrict__ W,
                                              float* __restrict__ C, int n) {
    constexpr int KT = 32;
    constexpr int ROWS = 128;
    constexpr int CG = DOUT / 4;     // col groups: 32 or 16
    constexpr int RPT = ROWS / (256 / CG);  // rows per thread: 16 or 8
    constexpr int XP = ROWS + 4;     // padded k-row stride (16B aligned)
    __shared__ float ldsW[KT * DOUT];
    __shared__ float ldsX[KT * XP];
    int tid = threadIdx.x;
    int rowbase = blockIdx.x * ROWS;
    int c0 = (tid % CG) * 4;
    int r0 = (tid / CG) * RPT;
    float acc[RPT][4];
#pragma unroll
    for (int i = 0; i < RPT; i++)
#pragma unroll
        for (int j = 0; j < 4; j++) acc[i][j] = 0.f;

    for (int kp = 0; kp < 128 / KT; kp++) {
        const float4* Wg = (const float4*)(W + kp * KT * DOUT);
        for (int i = tid; i < KT * DOUT / 4; i += 256) ((float4*)ldsW)[i] = Wg[i];
        // stage X transposed: ldsX[k][r]
        for (int i = tid; i < ROWS * KT / 4; i += 256) {
            int r = i & (ROWS - 1);
            int q = i >> 7;  // k-quad
            int gr = rowbase + r;
            float4 v = make_float4(0.f, 0.f, 0.f, 0.f);
            if (gr < n) v = *(const float4*)(A + (size_t)gr * DIN + kp * KT + q * 4);
            ldsX[(q * 4 + 0) * XP + r] = v.x;
            ldsX[(q * 4 + 1) * XP + r] = v.y;
            ldsX[(q * 4 + 2) * XP + r] = v.z;
            ldsX[(q * 4 + 3) * XP + r] = v.w;
        }
        __syncthreads();
#pragma unroll 2
        for (int k = 0; k < KT; k++) {
            float4 b = *(const float4*)(ldsW + k * DOUT + c0);
            float av[RPT];
#pragma unroll
            for (int q = 0; q < RPT / 4; q++) {
                float4 a0 = *(const float4*)(ldsX + k * XP + r0 + q * 4);
                av[q * 4 + 0] = a0.x; av[q * 4 + 1] = a0.y;
                av[q * 4 + 2] = a0.z; av[q * 4 + 3] = a0.w;
            }
#pragma unroll
            for (int i = 0; i < RPT; i++) {
                acc[i][0] = fmaf(av[i], b.x, acc[i][0]);
                acc[i][1] = fmaf(av[i], b.y, acc[i][1]);
                acc[i][2] = fmaf(av[i], b.z, acc[i][2]);
                acc[i][3] = fmaf(av[i], b.w, acc[i][3]);
            }
        }
        __syncthreads();
    }
#pragma unroll
    for (int i = 0; i < RPT; i++) {
        int gr = rowbase + r0 + i;
        if (gr < n)
            *(float4*)(C + (size_t)gr * DOUT + c0) =
                make_float4(acc[i][0], acc[i][1], acc[i][2], acc[i][3]);
    }
}

// ---------------- gather-aggregate: out[d] = bias + sum norm*xw[src] ----------------
// one wave per destination node. Lane l preloads meta[base+l] into a per-wave LDS
// strip (one coalesced vmem round-trip per 64 edges); broadcasts are same-address
// LDS reads (conflict-free, wave-synchronous). Gathers unrolled x8 for MLP.
template <int D, bool RELU>
__global__ __launch_bounds__(256) void aggregate_k(const float* __restrict__ xw,
                                                   const int* __restrict__ ptr,
                                                   const int2* __restrict__ meta,
                                                   const float* __restrict__ bias,
                                                   float* __restrict__ out, int n) {
    __shared__ int2 smeta[4][64];
    int lane = threadIdx.x & 63;
    int wid = threadIdx.x >> 6;
    int node = blockIdx.x * 4 + wid;
    if (node >= n) return;
    int e0 = ptr[node], e1 = ptr[node + 1];
    if (D == 128) {
        float2 bb = *(const float2*)(bias + lane * 2);
        const float* xp = xw + lane * 2;
        float ax = 0.f, ay = 0.f;
        for (int base = e0; base < e1; base += 64) {
            int cnt = min(e1 - base, 64);
            if (lane < cnt) smeta[wid][lane] = meta[base + lane];
            int j = 0;
            for (; j + 8 <= cnt; j += 8) {
                float2 v[8];
                float w[8];
#pragma unroll
                for (int u = 0; u < 8; u++) {
                    int2 m = smeta[wid][j + u];
                    w[u] = __int_as_float(m.y);
                    v[u] = *(const float2*)(xp + (size_t)m.x * 128);
                }
#pragma unroll
                for (int u = 0; u < 8; u++) {
                    ax = fmaf(w[u], v[u].x, ax);
                    ay = fmaf(w[u], v[u].y, ay);
                }
            }
            for (; j < cnt; j++) {
                int2 m = smeta[wid][j];
                float w0 = __int_as_float(m.y);
                float2 v = *(const float2*)(xp + (size_t)m.x * 128);
                ax = fmaf(w0, v.x, ax);
                ay = fmaf(w0, v.y, ay);
            }
        }
        ax += bb.x;
        ay += bb.y;
        if (RELU) { ax = fmaxf(ax, 0.f); ay = fmaxf(ay, 0.f); }
        *(float2*)(out + (size_t)node * 128 + lane * 2) = make_float2(ax, ay);
    } else {
        float bb = bias[lane];
        const float* xp = xw + lane;
        float a = 0.f;
        for (int base = e0; base < e1; base += 64) {
            int cnt = min(e1 - base, 64);
            if (lane < cnt) smeta[wid][lane] = meta[base + lane];
            int j = 0;
            for (; j + 8 <= cnt; j += 8) {
                float v[8];
                float w[8];
#pragma unroll
                for (int u = 0; u < 8; u++) {
                    int2 m = smeta[wid][j + u];
                    w[u] = __int_as_float(m.y);
                    v[u] = xp[(size_t)m.x * 64];
                }
#pragma unroll
                for (int u = 0; u < 8; u++) a = fmaf(w[u], v[u], a);
            }
            for (; j < cnt; j++) {
                int2 m = smeta[wid][j];
                a = fmaf(__int_as_float(m.y), xp[(size_t)m.x * 64], a);
            }
        }
        a += bb;
        if (RELU) a = fmaxf(a, 0.f);
        out[(size_t)node * 64 + lane] = a;
    }
}

extern "C" void kernel_launch(void* const* d_in, const int* in_sizes, int n_in,
                              void* d_out, int out_size, void* d_ws, size_t ws_size,
                              hipStream_t stream) {
    const float* x = (const float*)d_in[0];
    const int* ei = (const int*)d_in[1];
    const float* W1 = (const float*)d_in[2];
    const float* b1 = (const float*)d_in[3];
    const float* W2 = (const float*)d_in[4];
    const float* b2 = (const float*)d_in[5];
    const float* W3 = (const float*)d_in[6];
    const float* b3 = (const float*)d_in[7];
    float* out = (float*)d_out;
    int N = in_sizes[0] / 128;
    int E = in_sizes[1] / 2;
    const int* row = ei;
    const int* col = ei + E;
    int T = E + N;

    char* w = (char*)d_ws;
    size_t off = 0;
    auto alloc = [&](size_t bytes) -> void* {
        void* p = w + off;
        off = (off + bytes + 511) & ~(size_t)511;
        return p;
    };
    float* bufA = (float*)alloc((size_t)N * 128 * 4);
    float* bufB = (float*)alloc((size_t)N * 128 * 4);
    int* deg = (int*)alloc((size_t)N * 4);
    float* dinv = (float*)alloc((size_t)N * 4);
    int* cptr = (int*)alloc((size_t)(N + 1) * 4);
    int* cur = (int*)alloc((size_t)N * 4);
    int2* meta = (int2*)alloc((size_t)T * 8);
    int* bsum = (int*)alloc(4096);

    int nb = (N + 1023) / 1024;
    deg_init_k<<<(N + 255) / 256, 256, 0, stream>>>(deg, N);
    deg_count_k<<<(E + 255) / 256, 256, 0, stream>>>(col, E, deg);
    dinv_k<<<(N + 255) / 256, 256, 0, stream>>>(deg, dinv, N);
    scan_p1<<<nb, 256, 0, stream>>>(deg, N, bsum);
    scan_p2<<<1, 256, 0, stream>>>(bsum, nb);
    scan_p3<<<nb, 256, 0, stream>>>(deg, N, bsum, cptr, cur);
    fill_k<<<(T + 255) / 256, 256, 0, stream>>>(row, col, E, N, dinv, cur, meta);

    int gb = (N + 127) / 128;
    int ab = (N + 3) / 4;
    gemm_k<128><<<gb, 256, 0, stream>>>(x, W1, bufB, N);
    aggregate_k<128, true><<<ab, 256, 0, stream>>>(bufB, cptr, meta, b1, bufA, N);
    gemm_k<128><<<gb, 256, 0, stream>>>(bufA, W2, bufB, N);
    aggregate_k<128, true><<<ab, 256, 0, stream>>>(bufB, cptr, meta, b2, bufA, N);
    gemm_k<64><<<gb, 256, 0, stream>>>(bufA, W3, bufB, N);
    aggregate_k<64, false><<<ab, 256, 0, stream>>>(bufB, cptr, meta, b3, out, N);
}

// Round 5
// 582.828 us; speedup vs baseline: 1.5713x; 1.1937x over previous
//
#include <hip/hip_runtime.h>
#include <hip/hip_fp16.h>

#define DIN 128

// ---------------- degree / norm ----------------
__global__ __launch_bounds__(256) void deg_init_k(int* __restrict__ deg, int n) {
    int i = blockIdx.x * 256 + threadIdx.x;
    if (i < n) deg[i] = 1;  // self-loop
}

__global__ __launch_bounds__(256) void deg_count_k(const int* __restrict__ col, int e,
                                                   int* __restrict__ deg) {
    int i = blockIdx.x * 256 + threadIdx.x;
    if (i < e) atomicAdd(&deg[col[i]], 1);
}

__global__ __launch_bounds__(256) void dinv_k(const int* __restrict__ deg,
                                              float* __restrict__ dinv, int n) {
    int i = blockIdx.x * 256 + threadIdx.x;
    if (i < n) dinv[i] = rsqrtf((float)deg[i]);
}

// ---------------- 3-phase exclusive scan of deg -> col_ptr ----------------
__global__ __launch_bounds__(256) void scan_p1(const int* __restrict__ deg, int n,
                                               int* __restrict__ bsum) {
    __shared__ int lds[256];
    int t = threadIdx.x;
    int base = blockIdx.x * 1024 + t * 4;
    int s = 0;
#pragma unroll
    for (int i = 0; i < 4; i++) {
        int idx = base + i;
        if (idx < n) s += deg[idx];
    }
    lds[t] = s;
    __syncthreads();
    for (int o = 128; o > 0; o >>= 1) {
        if (t < o) lds[t] += lds[t + o];
        __syncthreads();
    }
    if (t == 0) bsum[blockIdx.x] = lds[0];
}

__global__ __launch_bounds__(256) void scan_p2(int* __restrict__ bsum, int nb) {
    __shared__ int lds[256];
    int t = threadIdx.x;
    int v = (t < nb) ? bsum[t] : 0;
    lds[t] = v;
    __syncthreads();
    for (int o = 1; o < 256; o <<= 1) {
        int tmp = 0;
        if (t >= o) tmp = lds[t - o];
        __syncthreads();
        lds[t] += tmp;
        __syncthreads();
    }
    if (t < nb) bsum[t] = lds[t] - v;  // exclusive
}

__global__ __launch_bounds__(256) void scan_p3(const int* __restrict__ deg, int n,
                                               const int* __restrict__ bsum,
                                               int* __restrict__ cptr,
                                               int* __restrict__ cur) {
    __shared__ int lds[256];
    int t = threadIdx.x;
    int base = blockIdx.x * 1024 + t * 4;
    int v[4];
    int s = 0;
#pragma unroll
    for (int i = 0; i < 4; i++) {
        int idx = base + i;
        v[i] = (idx < n) ? deg[idx] : 0;
        s += v[i];
    }
    lds[t] = s;
    __syncthreads();
    for (int o = 1; o < 256; o <<= 1) {
        int tmp = 0;
        if (t >= o) tmp = lds[t - o];
        __syncthreads();
        lds[t] += tmp;
        __syncthreads();
    }
    int off = bsum[blockIdx.x] + (lds[t] - s);
#pragma unroll
    for (int i = 0; i < 4; i++) {
        int idx = base + i;
        if (idx < n) {
            cptr[idx] = off;
            cur[idx] = off;
            off += v[i];
            if (idx == n - 1) cptr[n] = off;
        }
    }
}

// ---------------- bucket fill: packed (src, norm) per slot ----------------
__global__ __launch_bounds__(256) void fill_k(const int* __restrict__ row,
                                              const int* __restrict__ col, int E, int N,
                                              const float* __restrict__ dinv,
                                              int* __restrict__ cur,
                                              int2* __restrict__ meta) {
    int gid = blockIdx.x * 256 + threadIdx.x;
    int total = E + N;
    if (gid >= total) return;
    int s, d;
    if (gid < E) {
        s = row[gid];
        d = col[gid];
    } else {
        s = d = gid - E;  // self-loop
    }
    int p = atomicAdd(&cur[d], 1);
    float w = dinv[s] * dinv[d];
    meta[p] = make_int2(s, __float_as_int(w));
}

// ---------------- fp32 GEMM: C[n][DOUT] = A[n][128] @ W[128][DOUT], fp16 output ----
// 128-row tile per block, k-major X in LDS; compute fp32, store __half.
template <int DOUT>
__global__ __launch_bounds__(256) void gemm_k(const float* __restrict__ A,
                                              const float* __restrict__ W,
                                              __half* __restrict__ C, int n) {
    constexpr int KT = 32;
    constexpr int ROWS = 128;
    constexpr int CG = DOUT / 4;            // col groups: 32 or 16
    constexpr int RPT = ROWS / (256 / CG);  // rows per thread: 16 or 8
    constexpr int XP = ROWS + 4;            // padded k-row stride
    __shared__ float ldsW[KT * DOUT];
    __shared__ float ldsX[KT * XP];
    int tid = threadIdx.x;
    int rowbase = blockIdx.x * ROWS;
    int c0 = (tid % CG) * 4;
    int r0 = (tid / CG) * RPT;
    float acc[RPT][4];
#pragma unroll
    for (int i = 0; i < RPT; i++)
#pragma unroll
        for (int j = 0; j < 4; j++) acc[i][j] = 0.f;

    for (int kp = 0; kp < 128 / KT; kp++) {
        const float4* Wg = (const float4*)(W + kp * KT * DOUT);
        for (int i = tid; i < KT * DOUT / 4; i += 256) ((float4*)ldsW)[i] = Wg[i];
        for (int i = tid; i < ROWS * KT / 4; i += 256) {
            int r = i & (ROWS - 1);
            int q = i >> 7;  // k-quad
            int gr = rowbase + r;
            float4 v = make_float4(0.f, 0.f, 0.f, 0.f);
            if (gr < n) v = *(const float4*)(A + (size_t)gr * DIN + kp * KT + q * 4);
            ldsX[(q * 4 + 0) * XP + r] = v.x;
            ldsX[(q * 4 + 1) * XP + r] = v.y;
            ldsX[(q * 4 + 2) * XP + r] = v.z;
            ldsX[(q * 4 + 3) * XP + r] = v.w;
        }
        __syncthreads();
#pragma unroll 2
        for (int k = 0; k < KT; k++) {
            float4 b = *(const float4*)(ldsW + k * DOUT + c0);
            float av[RPT];
#pragma unroll
            for (int q = 0; q < RPT / 4; q++) {
                float4 a0 = *(const float4*)(ldsX + k * XP + r0 + q * 4);
                av[q * 4 + 0] = a0.x; av[q * 4 + 1] = a0.y;
                av[q * 4 + 2] = a0.z; av[q * 4 + 3] = a0.w;
            }
#pragma unroll
            for (int i = 0; i < RPT; i++) {
                acc[i][0] = fmaf(av[i], b.x, acc[i][0]);
                acc[i][1] = fmaf(av[i], b.y, acc[i][1]);
                acc[i][2] = fmaf(av[i], b.z, acc[i][2]);
                acc[i][3] = fmaf(av[i], b.w, acc[i][3]);
            }
        }
        __syncthreads();
    }
#pragma unroll
    for (int i = 0; i < RPT; i++) {
        int gr = rowbase + r0 + i;
        if (gr < n) {
            __half2 h01 = __floats2half2_rn(acc[i][0], acc[i][1]);
            __half2 h23 = __floats2half2_rn(acc[i][2], acc[i][3]);
            uint2 pk;
            pk.x = *(unsigned int*)&h01;
            pk.y = *(unsigned int*)&h23;
            *(uint2*)(C + (size_t)gr * DOUT + c0) = pk;
        }
    }
}

// ---------------- gather-aggregate: out[d] = bias + sum norm*xw_fp16[src] --------
// one wave per destination node; lane-preloaded meta via per-wave LDS strip;
// fp16 gathers (halved bytes/edge), fp32 accumulate, unroll x8.
template <int D, bool RELU>
__global__ __launch_bounds__(256) void aggregate_k(const __half* __restrict__ xw,
                                                   const int* __restrict__ ptr,
                                                   const int2* __restrict__ meta,
                                                   const float* __restrict__ bias,
                                                   float* __restrict__ out, int n) {
    __shared__ int2 smeta[4][64];
    int lane = threadIdx.x & 63;
    int wid = threadIdx.x >> 6;
    int node = blockIdx.x * 4 + wid;
    if (node >= n) return;
    int e0 = ptr[node], e1 = ptr[node + 1];
    if (D == 128) {
        float2 bb = *(const float2*)(bias + lane * 2);
        const __half* xp = xw + lane * 2;
        float ax = 0.f, ay = 0.f;
        for (int base = e0; base < e1; base += 64) {
            int cnt = min(e1 - base, 64);
            if (lane < cnt) smeta[wid][lane] = meta[base + lane];
            int j = 0;
            for (; j + 8 <= cnt; j += 8) {
                __half2 v[8];
                float w[8];
#pragma unroll
                for (int u = 0; u < 8; u++) {
                    int2 m = smeta[wid][j + u];
                    w[u] = __int_as_float(m.y);
                    v[u] = *(const __half2*)(xp + (size_t)m.x * 128);
                }
#pragma unroll
                for (int u = 0; u < 8; u++) {
                    float2 f = __half22float2(v[u]);
                    ax = fmaf(w[u], f.x, ax);
                    ay = fmaf(w[u], f.y, ay);
                }
            }
            for (; j < cnt; j++) {
                int2 m = smeta[wid][j];
                float w0 = __int_as_float(m.y);
                float2 f = __half22float2(*(const __half2*)(xp + (size_t)m.x * 128));
                ax = fmaf(w0, f.x, ax);
                ay = fmaf(w0, f.y, ay);
            }
        }
        ax += bb.x;
        ay += bb.y;
        if (RELU) { ax = fmaxf(ax, 0.f); ay = fmaxf(ay, 0.f); }
        *(float2*)(out + (size_t)node * 128 + lane * 2) = make_float2(ax, ay);
    } else {
        float bb = bias[lane];
        const __half* xp = xw + lane;
        float a = 0.f;
        for (int base = e0; base < e1; base += 64) {
            int cnt = min(e1 - base, 64);
            if (lane < cnt) smeta[wid][lane] = meta[base + lane];
            int j = 0;
            for (; j + 8 <= cnt; j += 8) {
                __half v[8];
                float w[8];
#pragma unroll
                for (int u = 0; u < 8; u++) {
                    int2 m = smeta[wid][j + u];
                    w[u] = __int_as_float(m.y);
                    v[u] = xp[(size_t)m.x * 64];
                }
#pragma unroll
                for (int u = 0; u < 8; u++) a = fmaf(w[u], __half2float(v[u]), a);
            }
            for (; j < cnt; j++) {
                int2 m = smeta[wid][j];
                a = fmaf(__int_as_float(m.y), __half2float(xp[(size_t)m.x * 64]), a);
            }
        }
        a += bb;
        if (RELU) a = fmaxf(a, 0.f);
        out[(size_t)node * 64 + lane] = a;
    }
}

extern "C" void kernel_launch(void* const* d_in, const int* in_sizes, int n_in,
                              void* d_out, int out_size, void* d_ws, size_t ws_size,
                              hipStream_t stream) {
    const float* x = (const float*)d_in[0];
    const int* ei = (const int*)d_in[1];
    const float* W1 = (const float*)d_in[2];
    const float* b1 = (const float*)d_in[3];
    const float* W2 = (const float*)d_in[4];
    const float* b2 = (const float*)d_in[5];
    const float* W3 = (const float*)d_in[6];
    const float* b3 = (const float*)d_in[7];
    float* out = (float*)d_out;
    int N = in_sizes[0] / 128;
    int E = in_sizes[1] / 2;
    const int* row = ei;
    const int* col = ei + E;
    int T = E + N;

    char* w = (char*)d_ws;
    size_t off = 0;
    auto alloc = [&](size_t bytes) -> void* {
        void* p = w + off;
        off = (off + bytes + 511) & ~(size_t)511;
        return p;
    };
    float* bufA = (float*)alloc((size_t)N * 128 * 4);    // fp32 hidden (GEMM input)
    __half* bufH = (__half*)alloc((size_t)N * 128 * 2);  // fp16 xw (gather source)
    int* deg = (int*)alloc((size_t)N * 4);
    float* dinv = (float*)alloc((size_t)N * 4);
    int* cptr = (int*)alloc((size_t)(N + 1) * 4);
    int* cur = (int*)alloc((size_t)N * 4);
    int2* meta = (int2*)alloc((size_t)T * 8);
    int* bsum = (int*)alloc(4096);

    int nb = (N + 1023) / 1024;
    deg_init_k<<<(N + 255) / 256, 256, 0, stream>>>(deg, N);
    deg_count_k<<<(E + 255) / 256, 256, 0, stream>>>(col, E, deg);
    dinv_k<<<(N + 255) / 256, 256, 0, stream>>>(deg, dinv, N);
    scan_p1<<<nb, 256, 0, stream>>>(deg, N, bsum);
    scan_p2<<<1, 256, 0, stream>>>(bsum, nb);
    scan_p3<<<nb, 256, 0, stream>>>(deg, N, bsum, cptr, cur);
    fill_k<<<(T + 255) / 256, 256, 0, stream>>>(row, col, E, N, dinv, cur, meta);

    int gb = (N + 127) / 128;
    int ab = (N + 3) / 4;
    gemm_k<128><<<gb, 256, 0, stream>>>(x, W1, bufH, N);
    aggregate_k<128, true><<<ab, 256, 0, stream>>>(bufH, cptr, meta, b1, bufA, N);
    gemm_k<128><<<gb, 256, 0, stream>>>(bufA, W2, bufH, N);
    aggregate_k<128, true><<<ab, 256, 0, stream>>>(bufH, cptr, meta, b2, bufA, N);
    gemm_k<64><<<gb, 256, 0, stream>>>(bufA, W3, bufH, N);
    aggregate_k<64, false><<<ab, 256, 0, stream>>>(bufH, cptr, meta, b3, out, N);
}

// Round 6
// 532.481 us; speedup vs baseline: 1.7199x; 1.0946x over previous
//
#include <hip/hip_runtime.h>
#include <hip/hip_fp16.h>

typedef _Float16 half8 __attribute__((ext_vector_type(8)));
typedef float floatx4 __attribute__((ext_vector_type(4)));

// ---------------- degree / norm ----------------
__global__ __launch_bounds__(256) void deg_init_k(int* __restrict__ deg, int n) {
    int i = blockIdx.x * 256 + threadIdx.x;
    if (i < n) deg[i] = 1;  // self-loop
}

__global__ __launch_bounds__(256) void deg_count_k(const int* __restrict__ col, int e,
                                                   int* __restrict__ deg) {
    int i = blockIdx.x * 256 + threadIdx.x;
    if (i < e) atomicAdd(&deg[col[i]], 1);
}

__global__ __launch_bounds__(256) void dinv_k(const int* __restrict__ deg,
                                              float* __restrict__ dinv, int n) {
    int i = blockIdx.x * 256 + threadIdx.x;
    if (i < n) dinv[i] = rsqrtf((float)deg[i]);
}

// ---------------- weight convert + transpose: Wt[n][k] = (half)W[k][n] ----------
__global__ __launch_bounds__(256) void wconv_k(const float* __restrict__ W1,
                                               const float* __restrict__ W2,
                                               const float* __restrict__ W3,
                                               __half* __restrict__ Wt1,
                                               __half* __restrict__ Wt2,
                                               __half* __restrict__ Wt3) {
    int idx = blockIdx.x * 256 + threadIdx.x;
    if (idx < 16384) {
        int k = idx >> 7, nn = idx & 127;
        Wt1[nn * 128 + k] = __float2half(W1[idx]);
    } else if (idx < 32768) {
        int j = idx - 16384;
        int k = j >> 7, nn = j & 127;
        Wt2[nn * 128 + k] = __float2half(W2[j]);
    } else if (idx < 40960) {
        int j = idx - 32768;
        int k = j >> 6, nn = j & 63;
        Wt3[nn * 128 + k] = __float2half(W3[j]);
    }
}

// ---------------- 3-phase exclusive scan of deg -> col_ptr ----------------
__global__ __launch_bounds__(256) void scan_p1(const int* __restrict__ deg, int n,
                                               int* __restrict__ bsum) {
    __shared__ int lds[256];
    int t = threadIdx.x;
    int base = blockIdx.x * 1024 + t * 4;
    int s = 0;
#pragma unroll
    for (int i = 0; i < 4; i++) {
        int idx = base + i;
        if (idx < n) s += deg[idx];
    }
    lds[t] = s;
    __syncthreads();
    for (int o = 128; o > 0; o >>= 1) {
        if (t < o) lds[t] += lds[t + o];
        __syncthreads();
    }
    if (t == 0) bsum[blockIdx.x] = lds[0];
}

__global__ __launch_bounds__(256) void scan_p2(int* __restrict__ bsum, int nb) {
    __shared__ int lds[256];
    int t = threadIdx.x;
    int v = (t < nb) ? bsum[t] : 0;
    lds[t] = v;
    __syncthreads();
    for (int o = 1; o < 256; o <<= 1) {
        int tmp = 0;
        if (t >= o) tmp = lds[t - o];
        __syncthreads();
        lds[t] += tmp;
        __syncthreads();
    }
    if (t < nb) bsum[t] = lds[t] - v;  // exclusive
}

__global__ __launch_bounds__(256) void scan_p3(const int* __restrict__ deg, int n,
                                               const int* __restrict__ bsum,
                                               int* __restrict__ cptr,
                                               int* __restrict__ cur) {
    __shared__ int lds[256];
    int t = threadIdx.x;
    int base = blockIdx.x * 1024 + t * 4;
    int v[4];
    int s = 0;
#pragma unroll
    for (int i = 0; i < 4; i++) {
        int idx = base + i;
        v[i] = (idx < n) ? deg[idx] : 0;
        s += v[i];
    }
    lds[t] = s;
    __syncthreads();
    for (int o = 1; o < 256; o <<= 1) {
        int tmp = 0;
        if (t >= o) tmp = lds[t - o];
        __syncthreads();
        lds[t] += tmp;
        __syncthreads();
    }
    int off = bsum[blockIdx.x] + (lds[t] - s);
#pragma unroll
    for (int i = 0; i < 4; i++) {
        int idx = base + i;
        if (idx < n) {
            cptr[idx] = off;
            cur[idx] = off;
            off += v[i];
            if (idx == n - 1) cptr[n] = off;
        }
    }
}

// ---------------- bucket fill: src-only meta via atomicExch (L2-resident line) ----
__global__ __launch_bounds__(256) void fill_k(const int* __restrict__ row,
                                              const int* __restrict__ col, int E, int N,
                                              int* __restrict__ cur,
                                              int* __restrict__ meta) {
    int gid = blockIdx.x * 256 + threadIdx.x;
    int total = E + N;
    if (gid >= total) return;
    int s, d;
    if (gid < E) {
        s = row[gid];
        d = col[gid];
    } else {
        s = d = gid - E;  // self-loop
    }
    int p = atomicAdd(&cur[d], 1);
    atomicExch(&meta[p], s);  // atomic -> performed at TCC -> line merges in L2
}

// ---------------- f16 MFMA GEMM: C[n][DOUT] = (half)(dinv[r] * A[n][128] @ W) ------
// 128-row tile per block, 4 waves x 32 rows. A-frags loaded direct from global in
// MFMA fragment layout; Wt (pre-transposed [DOUT][128]) staged in LDS, pad stride 136.
template <typename AT, int DOUT>
__global__ __launch_bounds__(256) void gemm_mfma(const AT* __restrict__ A,
                                                 const __half* __restrict__ Wt,
                                                 const float* __restrict__ dinv,
                                                 __half* __restrict__ C, int n) {
    constexpr int CT = DOUT / 16;  // col tiles: 8 or 4
    constexpr int WP = 136;        // padded LDS stride (halves): 2-way banks, 16B aligned
    __shared__ _Float16 ldsW[DOUT * WP];
    int tid = threadIdx.x;
    int lane = tid & 63;
    int wid = tid >> 6;
    // stage Wt into LDS
    for (int i = tid; i < DOUT * 16; i += 256) {
        int nrow = i >> 4;
        int kc = (i & 15) * 8;
        *(half8*)(&ldsW[nrow * WP + kc]) =
            *(const half8*)((const _Float16*)Wt + nrow * 128 + kc);
    }
    __syncthreads();
    int rwb = blockIdx.x * 128 + wid * 32;
    int m = lane & 15;
    int quad = lane >> 4;
    floatx4 acc[2][CT];
#pragma unroll
    for (int t = 0; t < 2; t++)
#pragma unroll
        for (int c = 0; c < CT; c++) acc[t][c] = (floatx4){0.f, 0.f, 0.f, 0.f};

#pragma unroll
    for (int kq = 0; kq < 4; kq++) {
        int k0 = kq * 32 + quad * 8;
        half8 afr[2];
#pragma unroll
        for (int t = 0; t < 2; t++) {
            int r = rwb + t * 16 + m;
            r = r < n ? r : n - 1;  // clamp (results unused for OOB rows)
            const AT* ap = A + (size_t)r * 128 + k0;
            if constexpr (sizeof(AT) == 2) {
                afr[t] = *(const half8*)ap;
            } else {
                float4 f0 = *(const float4*)ap;
                float4 f1 = *(const float4*)(ap + 4);
                half8 h;
                h[0] = (_Float16)f0.x; h[1] = (_Float16)f0.y;
                h[2] = (_Float16)f0.z; h[3] = (_Float16)f0.w;
                h[4] = (_Float16)f1.x; h[5] = (_Float16)f1.y;
                h[6] = (_Float16)f1.z; h[7] = (_Float16)f1.w;
                afr[t] = h;
            }
        }
#pragma unroll
        for (int c = 0; c < CT; c++) {
            half8 bfr = *(const half8*)(&ldsW[(c * 16 + m) * WP + k0]);
#pragma unroll
            for (int t = 0; t < 2; t++)
                acc[t][c] =
                    __builtin_amdgcn_mfma_f32_16x16x32_f16(afr[t], bfr, acc[t][c], 0, 0, 0);
        }
    }
    // epilogue: C/D layout col=lane&15, row=quad*4+reg; scale row by dinv[r]
#pragma unroll
    for (int t = 0; t < 2; t++) {
#pragma unroll
        for (int reg = 0; reg < 4; reg++) {
            int r = rwb + t * 16 + quad * 4 + reg;
            if (r < n) {
                float dv = dinv[r];
#pragma unroll
                for (int c = 0; c < CT; c++)
                    C[(size_t)r * DOUT + c * 16 + m] = __float2half(acc[t][c][reg] * dv);
            }
        }
    }
}

// ---------------- gather-aggregate: out[d] = dinv[d] * sum xw[src] + bias ----------
// xw rows already scaled by dinv[src]. One wave per dst node; lane-preloaded meta via
// per-wave LDS strip; fp16 gathers, fp32 accumulate, unroll x8.
template <int D, bool RELU, typename OT>
__global__ __launch_bounds__(256) void aggregate_k(const __half* __restrict__ xw,
                                                   const int* __restrict__ ptr,
                                                   const int* __restrict__ meta,
                                                   const float* __restrict__ bias,
                                                   const float* __restrict__ dinv,
                                                   OT* __restrict__ out, int n) {
    __shared__ int smeta[4][64];
    int lane = threadIdx.x & 63;
    int wid = threadIdx.x >> 6;
    int node = blockIdx.x * 4 + wid;
    if (node >= n) return;
    int e0 = ptr[node], e1 = ptr[node + 1];
    float dv = dinv[node];
    if (D == 128) {
        float2 bb = *(const float2*)(bias + lane * 2);
        const __half* xp = xw + lane * 2;
        float ax = 0.f, ay = 0.f;
        for (int base = e0; base < e1; base += 64) {
            int cnt = min(e1 - base, 64);
            if (lane < cnt) smeta[wid][lane] = meta[base + lane];
            int j = 0;
            for (; j + 8 <= cnt; j += 8) {
                __half2 v[8];
#pragma unroll
                for (int u = 0; u < 8; u++) {
                    int s = smeta[wid][j + u];
                    v[u] = *(const __half2*)(xp + (size_t)s * 128);
                }
#pragma unroll
                for (int u = 0; u < 8; u++) {
                    float2 f = __half22float2(v[u]);
                    ax += f.x;
                    ay += f.y;
                }
            }
            for (; j < cnt; j++) {
                int s = smeta[wid][j];
                float2 f = __half22float2(*(const __half2*)(xp + (size_t)s * 128));
                ax += f.x;
                ay += f.y;
            }
        }
        ax = ax * dv + bb.x;
        ay = ay * dv + bb.y;
        if (RELU) { ax = fmaxf(ax, 0.f); ay = fmaxf(ay, 0.f); }
        if constexpr (sizeof(OT) == 2) {
            *(__half2*)((__half*)out + (size_t)node * 128 + lane * 2) =
                __floats2half2_rn(ax, ay);
        } else {
            *(float2*)((float*)out + (size_t)node * 128 + lane * 2) = make_float2(ax, ay);
        }
    } else {
        float bb = bias[lane];
        const __half* xp = xw + lane;
        float a = 0.f;
        for (int base = e0; base < e1; base += 64) {
            int cnt = min(e1 - base, 64);
            if (lane < cnt) smeta[wid][lane] = meta[base + lane];
            int j = 0;
            for (; j + 8 <= cnt; j += 8) {
                __half v[8];
#pragma unroll
                for (int u = 0; u < 8; u++) {
                    int s = smeta[wid][j + u];
                    v[u] = xp[(size_t)s * 64];
                }
#pragma unroll
                for (int u = 0; u < 8; u++) a += __half2float(v[u]);
            }
            for (; j < cnt; j++) {
                int s = smeta[wid][j];
                a += __half2float(xp[(size_t)s * 64]);
            }
        }
        a = a * dv + bb;
        if (RELU) a = fmaxf(a, 0.f);
        if constexpr (sizeof(OT) == 2)
            ((__half*)out)[(size_t)node * 64 + lane] = __float2half(a);
        else
            ((float*)out)[(size_t)node * 64 + lane] = a;
    }
}

extern "C" void kernel_launch(void* const* d_in, const int* in_sizes, int n_in,
                              void* d_out, int out_size, void* d_ws, size_t ws_size,
                              hipStream_t stream) {
    const float* x = (const float*)d_in[0];
    const int* ei = (const int*)d_in[1];
    const float* W1 = (const float*)d_in[2];
    const float* b1 = (const float*)d_in[3];
    const float* W2 = (const float*)d_in[4];
    const float* b2 = (const float*)d_in[5];
    const float* W3 = (const float*)d_in[6];
    const float* b3 = (const float*)d_in[7];
    float* out = (float*)d_out;
    int N = in_sizes[0] / 128;
    int E = in_sizes[1] / 2;
    const int* row = ei;
    const int* col = ei + E;
    int T = E + N;

    char* w = (char*)d_ws;
    size_t off = 0;
    auto alloc = [&](size_t bytes) -> void* {
        void* p = w + off;
        off = (off + bytes + 511) & ~(size_t)511;
        return p;
    };
    __half* bufH = (__half*)alloc((size_t)N * 128 * 2);   // xw (dinv-scaled, fp16)
    __half* bufA = (__half*)alloc((size_t)N * 128 * 2);   // hidden h (fp16 GEMM input)
    __half* Wt1 = (__half*)alloc(16384 * 2);
    __half* Wt2 = (__half*)alloc(16384 * 2);
    __half* Wt3 = (__half*)alloc(8192 * 2);
    int* deg = (int*)alloc((size_t)N * 4);
    float* dinv = (float*)alloc((size_t)N * 4);
    int* cptr = (int*)alloc((size_t)(N + 1) * 4);
    int* cur = (int*)alloc((size_t)N * 4);
    int* meta = (int*)alloc((size_t)T * 4);
    int* bsum = (int*)alloc(4096);

    int nb = (N + 1023) / 1024;
    wconv_k<<<160, 256, 0, stream>>>(W1, W2, W3, Wt1, Wt2, Wt3);
    deg_init_k<<<(N + 255) / 256, 256, 0, stream>>>(deg, N);
    deg_count_k<<<(E + 255) / 256, 256, 0, stream>>>(col, E, deg);
    dinv_k<<<(N + 255) / 256, 256, 0, stream>>>(deg, dinv, N);
    scan_p1<<<nb, 256, 0, stream>>>(deg, N, bsum);
    scan_p2<<<1, 256, 0, stream>>>(bsum, nb);
    scan_p3<<<nb, 256, 0, stream>>>(deg, N, bsum, cptr, cur);
    fill_k<<<(T + 255) / 256, 256, 0, stream>>>(row, col, E, N, cur, meta);

    int gb = (N + 127) / 128;
    int ab = (N + 3) / 4;
    gemm_mfma<float, 128><<<gb, 256, 0, stream>>>(x, Wt1, dinv, bufH, N);
    aggregate_k<128, true, __half><<<ab, 256, 0, stream>>>(bufH, cptr, meta, b1, dinv, bufA, N);
    gemm_mfma<__half, 128><<<gb, 256, 0, stream>>>(bufA, Wt2, dinv, bufH, N);
    aggregate_k<128, true, __half><<<ab, 256, 0, stream>>>(bufH, cptr, meta, b2, dinv, bufA, N);
    gemm_mfma<__half, 64><<<gb, 256, 0, stream>>>(bufA, Wt3, dinv, bufH, N);
    aggregate_k<64, false, float><<<ab, 256, 0, stream>>>(bufH, cptr, meta, b3, dinv, out, N);
}

// Round 7
// 504.809 us; speedup vs baseline: 1.8142x; 1.0548x over previous
//
#include <hip/hip_runtime.h>
#include <hip/hip_fp16.h>

typedef _Float16 half8 __attribute__((ext_vector_type(8)));
typedef float floatx4 __attribute__((ext_vector_type(4)));

// ---------------- degree / norm ----------------
__global__ __launch_bounds__(256) void deg_init_k(int* __restrict__ deg, int n) {
    int i = blockIdx.x * 256 + threadIdx.x;
    if (i < n) deg[i] = 1;  // self-loop
}

__global__ __launch_bounds__(256) void deg_count_k(const int* __restrict__ col, int e,
                                                   int* __restrict__ deg) {
    int i = blockIdx.x * 256 + threadIdx.x;
    if (i < e) atomicAdd(&deg[col[i]], 1);
}

__global__ __launch_bounds__(256) void dinv_k(const int* __restrict__ deg,
                                              float* __restrict__ dinv, int n) {
    int i = blockIdx.x * 256 + threadIdx.x;
    if (i < n) dinv[i] = rsqrtf((float)deg[i]);
}

// ---------------- weight convert + transpose: Wt[n][k] = (half)W[k][n] ----------
__global__ __launch_bounds__(256) void wconv_k(const float* __restrict__ W1,
                                               const float* __restrict__ W2,
                                               const float* __restrict__ W3,
                                               __half* __restrict__ Wt1,
                                               __half* __restrict__ Wt2,
                                               __half* __restrict__ Wt3) {
    int idx = blockIdx.x * 256 + threadIdx.x;
    if (idx < 16384) {
        int k = idx >> 7, nn = idx & 127;
        Wt1[nn * 128 + k] = __float2half(W1[idx]);
    } else if (idx < 32768) {
        int j = idx - 16384;
        int k = j >> 7, nn = j & 127;
        Wt2[nn * 128 + k] = __float2half(W2[j]);
    } else if (idx < 40960) {
        int j = idx - 32768;
        int k = j >> 6, nn = j & 63;
        Wt3[nn * 128 + k] = __float2half(W3[j]);
    }
}

// ---------------- 3-phase exclusive scan of deg -> col_ptr ----------------
__global__ __launch_bounds__(256) void scan_p1(const int* __restrict__ deg, int n,
                                               int* __restrict__ bsum) {
    __shared__ int lds[256];
    int t = threadIdx.x;
    int base = blockIdx.x * 1024 + t * 4;
    int s = 0;
#pragma unroll
    for (int i = 0; i < 4; i++) {
        int idx = base + i;
        if (idx < n) s += deg[idx];
    }
    lds[t] = s;
    __syncthreads();
    for (int o = 128; o > 0; o >>= 1) {
        if (t < o) lds[t] += lds[t + o];
        __syncthreads();
    }
    if (t == 0) bsum[blockIdx.x] = lds[0];
}

__global__ __launch_bounds__(256) void scan_p2(int* __restrict__ bsum, int nb) {
    __shared__ int lds[256];
    int t = threadIdx.x;
    int v = (t < nb) ? bsum[t] : 0;
    lds[t] = v;
    __syncthreads();
    for (int o = 1; o < 256; o <<= 1) {
        int tmp = 0;
        if (t >= o) tmp = lds[t - o];
        __syncthreads();
        lds[t] += tmp;
        __syncthreads();
    }
    if (t < nb) bsum[t] = lds[t] - v;  // exclusive
}

__global__ __launch_bounds__(256) void scan_p3(const int* __restrict__ deg, int n,
                                               const int* __restrict__ bsum,
                                               int* __restrict__ cptr,
                                               int* __restrict__ cur) {
    __shared__ int lds[256];
    int t = threadIdx.x;
    int base = blockIdx.x * 1024 + t * 4;
    int v[4];
    int s = 0;
#pragma unroll
    for (int i = 0; i < 4; i++) {
        int idx = base + i;
        v[i] = (idx < n) ? deg[idx] : 0;
        s += v[i];
    }
    lds[t] = s;
    __syncthreads();
    for (int o = 1; o < 256; o <<= 1) {
        int tmp = 0;
        if (t >= o) tmp = lds[t - o];
        __syncthreads();
        lds[t] += tmp;
        __syncthreads();
    }
    int off = bsum[blockIdx.x] + (lds[t] - s);
#pragma unroll
    for (int i = 0; i < 4; i++) {
        int idx = base + i;
        if (idx < n) {
            cptr[idx] = off;
            cur[idx] = off;
            off += v[i];
            if (idx == n - 1) cptr[n] = off;
        }
    }
}

// ---------------- bucket fill: src-only meta, plain scattered store ----------------
__global__ __launch_bounds__(256) void fill_k(const int* __restrict__ row,
                                              const int* __restrict__ col, int E, int N,
                                              int* __restrict__ cur,
                                              int* __restrict__ meta) {
    int gid = blockIdx.x * 256 + threadIdx.x;
    int total = E + N;
    if (gid >= total) return;
    int s, d;
    if (gid < E) {
        s = row[gid];
        d = col[gid];
    } else {
        s = d = gid - E;  // self-loop
    }
    int p = atomicAdd(&cur[d], 1);
    meta[p] = s;
}

// ---------------- f16 MFMA GEMM: C[n][DOUT] = (half)(dinv[r] * A[n][128] @ W) ------
// 128-row tile per block, 4 waves x 32 rows. A-frags loaded direct from global in
// MFMA fragment layout; Wt (pre-transposed [DOUT][128]) staged in LDS, pad stride 136.
template <typename AT, int DOUT>
__global__ __launch_bounds__(256) void gemm_mfma(const AT* __restrict__ A,
                                                 const __half* __restrict__ Wt,
                                                 const float* __restrict__ dinv,
                                                 __half* __restrict__ C, int n) {
    constexpr int CT = DOUT / 16;  // col tiles: 8 or 4
    constexpr int WP = 136;        // padded LDS stride (halves)
    __shared__ _Float16 ldsW[DOUT * WP];
    int tid = threadIdx.x;
    int lane = tid & 63;
    int wid = tid >> 6;
    for (int i = tid; i < DOUT * 16; i += 256) {
        int nrow = i >> 4;
        int kc = (i & 15) * 8;
        *(half8*)(&ldsW[nrow * WP + kc]) =
            *(const half8*)((const _Float16*)Wt + nrow * 128 + kc);
    }
    __syncthreads();
    int rwb = blockIdx.x * 128 + wid * 32;
    int m = lane & 15;
    int quad = lane >> 4;
    floatx4 acc[2][CT];
#pragma unroll
    for (int t = 0; t < 2; t++)
#pragma unroll
        for (int c = 0; c < CT; c++) acc[t][c] = (floatx4){0.f, 0.f, 0.f, 0.f};

#pragma unroll
    for (int kq = 0; kq < 4; kq++) {
        int k0 = kq * 32 + quad * 8;
        half8 afr[2];
#pragma unroll
        for (int t = 0; t < 2; t++) {
            int r = rwb + t * 16 + m;
            r = r < n ? r : n - 1;  // clamp (results unused for OOB rows)
            const AT* ap = A + (size_t)r * 128 + k0;
            if constexpr (sizeof(AT) == 2) {
                afr[t] = *(const half8*)ap;
            } else {
                float4 f0 = *(const float4*)ap;
                float4 f1 = *(const float4*)(ap + 4);
                half8 h;
                h[0] = (_Float16)f0.x; h[1] = (_Float16)f0.y;
                h[2] = (_Float16)f0.z; h[3] = (_Float16)f0.w;
                h[4] = (_Float16)f1.x; h[5] = (_Float16)f1.y;
                h[6] = (_Float16)f1.z; h[7] = (_Float16)f1.w;
                afr[t] = h;
            }
        }
#pragma unroll
        for (int c = 0; c < CT; c++) {
            half8 bfr = *(const half8*)(&ldsW[(c * 16 + m) * WP + k0]);
#pragma unroll
            for (int t = 0; t < 2; t++)
                acc[t][c] =
                    __builtin_amdgcn_mfma_f32_16x16x32_f16(afr[t], bfr, acc[t][c], 0, 0, 0);
        }
    }
#pragma unroll
    for (int t = 0; t < 2; t++) {
#pragma unroll
        for (int reg = 0; reg < 4; reg++) {
            int r = rwb + t * 16 + quad * 4 + reg;
            if (r < n) {
                float dv = dinv[r];
#pragma unroll
                for (int c = 0; c < CT; c++)
                    C[(size_t)r * DOUT + c * 16 + m] = __float2half(acc[t][c][reg] * dv);
            }
        }
    }
}

// ---------------- gather-aggregate: out[d] = dinv[d] * sum xw[src] + bias ----------
// One wave per dst node. half8 (16B) per-lane gathers: GS lanes cover one row, so a
// wave-load covers EPW edges -> 4x bytes per TA address slot vs half2 gathers.
// Cross-lane shfl_xor reduce at the end; fp32 accumulate throughout.
template <int D, bool RELU, typename OT>
__global__ __launch_bounds__(256) void aggregate_k(const __half* __restrict__ xw,
                                                   const int* __restrict__ ptr,
                                                   const int* __restrict__ meta,
                                                   const float* __restrict__ bias,
                                                   const float* __restrict__ dinv,
                                                   OT* __restrict__ out, int n) {
    constexpr int GS = D / 8;    // lanes per row (16 or 8)
    constexpr int EPW = 64 / GS; // edges per wave-load (4 or 8)
    __shared__ int smeta[4][64];
    int lane = threadIdx.x & 63;
    int wid = threadIdx.x >> 6;
    int node = blockIdx.x * 4 + wid;
    if (node >= n) return;
    int e0 = ptr[node], e1 = ptr[node + 1];
    float dv = dinv[node];
    int sub = lane / GS;   // edge sub-slot
    int cg = lane % GS;    // column group: cols [cg*8, cg*8+8)
    const _Float16* xp = (const _Float16*)xw + cg * 8;
    float acc[8];
#pragma unroll
    for (int i = 0; i < 8; i++) acc[i] = 0.f;

    for (int base = e0; base < e1; base += 64) {
        int cnt = min(e1 - base, 64);
        if (lane < cnt) smeta[wid][lane] = meta[base + lane];
        for (int j = 0; j < cnt; j += EPW) {
            int e = j + sub;
            bool valid = e < cnt;
            int s = smeta[wid][valid ? e : 0];
            half8 v = *(const half8*)(xp + (size_t)s * D);
            float msk = valid ? 1.f : 0.f;
#pragma unroll
            for (int i = 0; i < 8; i++) acc[i] = fmaf(msk, (float)v[i], acc[i]);
        }
    }
    // reduce across edge sub-slots (lanes sharing cg)
#pragma unroll
    for (int off = GS; off < 64; off <<= 1) {
#pragma unroll
        for (int i = 0; i < 8; i++) acc[i] += __shfl_xor(acc[i], off, 64);
    }
    if (lane < GS) {
        float4 bb0 = *(const float4*)(bias + cg * 8);
        float4 bb1 = *(const float4*)(bias + cg * 8 + 4);
        float r[8];
        r[0] = acc[0] * dv + bb0.x; r[1] = acc[1] * dv + bb0.y;
        r[2] = acc[2] * dv + bb0.z; r[3] = acc[3] * dv + bb0.w;
        r[4] = acc[4] * dv + bb1.x; r[5] = acc[5] * dv + bb1.y;
        r[6] = acc[6] * dv + bb1.z; r[7] = acc[7] * dv + bb1.w;
        if (RELU) {
#pragma unroll
            for (int i = 0; i < 8; i++) r[i] = fmaxf(r[i], 0.f);
        }
        if constexpr (sizeof(OT) == 2) {
            half8 h;
#pragma unroll
            for (int i = 0; i < 8; i++) h[i] = (_Float16)r[i];
            *(half8*)((_Float16*)out + (size_t)node * D + cg * 8) = h;
        } else {
            float* op = (float*)out + (size_t)node * D + cg * 8;
            *(float4*)op = make_float4(r[0], r[1], r[2], r[3]);
            *(float4*)(op + 4) = make_float4(r[4], r[5], r[6], r[7]);
        }
    }
}

extern "C" void kernel_launch(void* const* d_in, const int* in_sizes, int n_in,
                              void* d_out, int out_size, void* d_ws, size_t ws_size,
                              hipStream_t stream) {
    const float* x = (const float*)d_in[0];
    const int* ei = (const int*)d_in[1];
    const float* W1 = (const float*)d_in[2];
    const float* b1 = (const float*)d_in[3];
    const float* W2 = (const float*)d_in[4];
    const float* b2 = (const float*)d_in[5];
    const float* W3 = (const float*)d_in[6];
    const float* b3 = (const float*)d_in[7];
    float* out = (float*)d_out;
    int N = in_sizes[0] / 128;
    int E = in_sizes[1] / 2;
    const int* row = ei;
    const int* col = ei + E;
    int T = E + N;

    char* w = (char*)d_ws;
    size_t off = 0;
    auto alloc = [&](size_t bytes) -> void* {
        void* p = w + off;
        off = (off + bytes + 511) & ~(size_t)511;
        return p;
    };
    __half* bufH = (__half*)alloc((size_t)N * 128 * 2);   // xw (dinv-scaled, fp16)
    __half* bufA = (__half*)alloc((size_t)N * 128 * 2);   // hidden h (fp16 GEMM input)
    __half* Wt1 = (__half*)alloc(16384 * 2);
    __half* Wt2 = (__half*)alloc(16384 * 2);
    __half* Wt3 = (__half*)alloc(8192 * 2);
    int* deg = (int*)alloc((size_t)N * 4);
    float* dinv = (float*)alloc((size_t)N * 4);
    int* cptr = (int*)alloc((size_t)(N + 1) * 4);
    int* cur = (int*)alloc((size_t)N * 4);
    int* meta = (int*)alloc((size_t)T * 4);
    int* bsum = (int*)alloc(4096);

    int nb = (N + 1023) / 1024;
    wconv_k<<<160, 256, 0, stream>>>(W1, W2, W3, Wt1, Wt2, Wt3);
    deg_init_k<<<(N + 255) / 256, 256, 0, stream>>>(deg, N);
    deg_count_k<<<(E + 255) / 256, 256, 0, stream>>>(col, E, deg);
    dinv_k<<<(N + 255) / 256, 256, 0, stream>>>(deg, dinv, N);
    scan_p1<<<nb, 256, 0, stream>>>(deg, N, bsum);
    scan_p2<<<1, 256, 0, stream>>>(bsum, nb);
    scan_p3<<<nb, 256, 0, stream>>>(deg, N, bsum, cptr, cur);
    fill_k<<<(T + 255) / 256, 256, 0, stream>>>(row, col, E, N, cur, meta);

    int gb = (N + 127) / 128;
    int ab = (N + 3) / 4;
    gemm_mfma<float, 128><<<gb, 256, 0, stream>>>(x, Wt1, dinv, bufH, N);
    aggregate_k<128, true, __half><<<ab, 256, 0, stream>>>(bufH, cptr, meta, b1, dinv, bufA, N);
    gemm_mfma<__half, 128><<<gb, 256, 0, stream>>>(bufA, Wt2, dinv, bufH, N);
    aggregate_k<128, true, __half><<<ab, 256, 0, stream>>>(bufH, cptr, meta, b2, dinv, bufA, N);
    gemm_mfma<__half, 64><<<gb, 256, 0, stream>>>(bufA, Wt3, dinv, bufH, N);
    aggregate_k<64, false, float><<<ab, 256, 0, stream>>>(bufH, cptr, meta, b3, dinv, out, N);
}

// Round 8
// 457.220 us; speedup vs baseline: 2.0030x; 1.1041x over previous
//
#include <hip/hip_runtime.h>
#include <hip/hip_fp16.h>

typedef _Float16 half8 __attribute__((ext_vector_type(8)));
typedef float floatx4 __attribute__((ext_vector_type(4)));

// ---------------- degree / norm ----------------
__global__ __launch_bounds__(256) void deg_init_k(int* __restrict__ deg, int n) {
    int i = blockIdx.x * 256 + threadIdx.x;
    if (i < n) deg[i] = 1;  // self-loop
}

__global__ __launch_bounds__(256) void deg_count_k(const int* __restrict__ col, int e,
                                                   int* __restrict__ deg) {
    int i = blockIdx.x * 256 + threadIdx.x;
    if (i < e) atomicAdd(&deg[col[i]], 1);
}

__global__ __launch_bounds__(256) void dinv_k(const int* __restrict__ deg,
                                              float* __restrict__ dinv, int n) {
    int i = blockIdx.x * 256 + threadIdx.x;
    if (i < n) dinv[i] = rsqrtf((float)deg[i]);
}

// ---------------- weight convert + transpose: Wt[n][k] = (half)W[k][n] ----------
__global__ __launch_bounds__(256) void wconv_k(const float* __restrict__ W1,
                                               const float* __restrict__ W2,
                                               const float* __restrict__ W3,
                                               __half* __restrict__ Wt1,
                                               __half* __restrict__ Wt2,
                                               __half* __restrict__ Wt3) {
    int idx = blockIdx.x * 256 + threadIdx.x;
    if (idx < 16384) {
        int k = idx >> 7, nn = idx & 127;
        Wt1[nn * 128 + k] = __float2half(W1[idx]);
    } else if (idx < 32768) {
        int j = idx - 16384;
        int k = j >> 7, nn = j & 127;
        Wt2[nn * 128 + k] = __float2half(W2[j]);
    } else if (idx < 40960) {
        int j = idx - 32768;
        int k = j >> 6, nn = j & 63;
        Wt3[nn * 128 + k] = __float2half(W3[j]);
    }
}

// ---------------- 3-phase exclusive scan of deg -> col_ptr ----------------
__global__ __launch_bounds__(256) void scan_p1(const int* __restrict__ deg, int n,
                                               int* __restrict__ bsum) {
    __shared__ int lds[256];
    int t = threadIdx.x;
    int base = blockIdx.x * 1024 + t * 4;
    int s = 0;
#pragma unroll
    for (int i = 0; i < 4; i++) {
        int idx = base + i;
        if (idx < n) s += deg[idx];
    }
    lds[t] = s;
    __syncthreads();
    for (int o = 128; o > 0; o >>= 1) {
        if (t < o) lds[t] += lds[t + o];
        __syncthreads();
    }
    if (t == 0) bsum[blockIdx.x] = lds[0];
}

__global__ __launch_bounds__(256) void scan_p2(int* __restrict__ bsum, int nb) {
    __shared__ int lds[256];
    int t = threadIdx.x;
    int v = (t < nb) ? bsum[t] : 0;
    lds[t] = v;
    __syncthreads();
    for (int o = 1; o < 256; o <<= 1) {
        int tmp = 0;
        if (t >= o) tmp = lds[t - o];
        __syncthreads();
        lds[t] += tmp;
        __syncthreads();
    }
    if (t < nb) bsum[t] = lds[t] - v;  // exclusive
}

__global__ __launch_bounds__(256) void scan_p3(const int* __restrict__ deg, int n,
                                               const int* __restrict__ bsum,
                                               int* __restrict__ cptr,
                                               int* __restrict__ cur) {
    __shared__ int lds[256];
    int t = threadIdx.x;
    int base = blockIdx.x * 1024 + t * 4;
    int v[4];
    int s = 0;
#pragma unroll
    for (int i = 0; i < 4; i++) {
        int idx = base + i;
        v[i] = (idx < n) ? deg[idx] : 0;
        s += v[i];
    }
    lds[t] = s;
    __syncthreads();
    for (int o = 1; o < 256; o <<= 1) {
        int tmp = 0;
        if (t >= o) tmp = lds[t - o];
        __syncthreads();
        lds[t] += tmp;
        __syncthreads();
    }
    int off = bsum[blockIdx.x] + (lds[t] - s);
#pragma unroll
    for (int i = 0; i < 4; i++) {
        int idx = base + i;
        if (idx < n) {
            cptr[idx] = off;
            cur[idx] = off;
            off += v[i];
            if (idx == n - 1) cptr[n] = off;
        }
    }
}

// ---------------- bucket fill: XCD-chunked counting-sort scatter ----------------
// 8 dst-range chunks; team k = blocks with blockIdx&7==k (round-robin -> same XCD).
// Each team grid-strides the full edge list and scatters only its own dst range, so
// every meta cache line is written by one XCD's L2 and written back once, full.
__global__ __launch_bounds__(256) void fill_k(const int* __restrict__ row,
                                              const int* __restrict__ col, int E, int N,
                                              int* __restrict__ cur,
                                              int* __restrict__ meta) {
    int chunkid = blockIdx.x & 7;
    int team = blockIdx.x >> 3;
    int nteams = gridDim.x >> 3;
    int chunk = (N + 7) >> 3;
    int dlo = chunkid * chunk;
    int dhi = min(N, dlo + chunk);
    int total = E + N;
    for (int i = team * 256 + threadIdx.x; i < total; i += nteams * 256) {
        int s, d;
        if (i < E) {
            s = row[i];
            d = col[i];
        } else {
            s = d = i - E;  // self-loop
        }
        if (d >= dlo && d < dhi) {
            int p = atomicAdd(&cur[d], 1);
            meta[p] = s;
        }
    }
}

// ---------------- f16 MFMA GEMM: C[n][DOUT] = (half)(dinv[r] * A[n][128] @ W) ------
template <typename AT, int DOUT>
__global__ __launch_bounds__(256) void gemm_mfma(const AT* __restrict__ A,
                                                 const __half* __restrict__ Wt,
                                                 const float* __restrict__ dinv,
                                                 __half* __restrict__ C, int n) {
    constexpr int CT = DOUT / 16;  // col tiles: 8 or 4
    constexpr int WP = 136;        // padded LDS stride (halves)
    __shared__ _Float16 ldsW[DOUT * WP];
    int tid = threadIdx.x;
    int lane = tid & 63;
    int wid = tid >> 6;
    for (int i = tid; i < DOUT * 16; i += 256) {
        int nrow = i >> 4;
        int kc = (i & 15) * 8;
        *(half8*)(&ldsW[nrow * WP + kc]) =
            *(const half8*)((const _Float16*)Wt + nrow * 128 + kc);
    }
    __syncthreads();
    int rwb = blockIdx.x * 128 + wid * 32;
    int m = lane & 15;
    int quad = lane >> 4;
    floatx4 acc[2][CT];
#pragma unroll
    for (int t = 0; t < 2; t++)
#pragma unroll
        for (int c = 0; c < CT; c++) acc[t][c] = (floatx4){0.f, 0.f, 0.f, 0.f};

#pragma unroll
    for (int kq = 0; kq < 4; kq++) {
        int k0 = kq * 32 + quad * 8;
        half8 afr[2];
#pragma unroll
        for (int t = 0; t < 2; t++) {
            int r = rwb + t * 16 + m;
            r = r < n ? r : n - 1;  // clamp (results unused for OOB rows)
            const AT* ap = A + (size_t)r * 128 + k0;
            if constexpr (sizeof(AT) == 2) {
                afr[t] = *(const half8*)ap;
            } else {
                float4 f0 = *(const float4*)ap;
                float4 f1 = *(const float4*)(ap + 4);
                half8 h;
                h[0] = (_Float16)f0.x; h[1] = (_Float16)f0.y;
                h[2] = (_Float16)f0.z; h[3] = (_Float16)f0.w;
                h[4] = (_Float16)f1.x; h[5] = (_Float16)f1.y;
                h[6] = (_Float16)f1.z; h[7] = (_Float16)f1.w;
                afr[t] = h;
            }
        }
#pragma unroll
        for (int c = 0; c < CT; c++) {
            half8 bfr = *(const half8*)(&ldsW[(c * 16 + m) * WP + k0]);
#pragma unroll
            for (int t = 0; t < 2; t++)
                acc[t][c] =
                    __builtin_amdgcn_mfma_f32_16x16x32_f16(afr[t], bfr, acc[t][c], 0, 0, 0);
        }
    }
#pragma unroll
    for (int t = 0; t < 2; t++) {
#pragma unroll
        for (int reg = 0; reg < 4; reg++) {
            int r = rwb + t * 16 + quad * 4 + reg;
            if (r < n) {
                float dv = dinv[r];
#pragma unroll
                for (int c = 0; c < CT; c++)
                    C[(size_t)r * DOUT + c * 16 + m] = __float2half(acc[t][c][reg] * dv);
            }
        }
    }
}

// ---------------- gather-aggregate: out[d] = dinv[d] * sum xw[src] + bias ----------
template <int D, bool RELU, typename OT>
__global__ __launch_bounds__(256) void aggregate_k(const __half* __restrict__ xw,
                                                   const int* __restrict__ ptr,
                                                   const int* __restrict__ meta,
                                                   const float* __restrict__ bias,
                                                   const float* __restrict__ dinv,
                                                   OT* __restrict__ out, int n) {
    constexpr int GS = D / 8;    // lanes per row (16 or 8)
    constexpr int EPW = 64 / GS; // edges per wave-load (4 or 8)
    __shared__ int smeta[4][64];
    int lane = threadIdx.x & 63;
    int wid = threadIdx.x >> 6;
    int node = blockIdx.x * 4 + wid;
    if (node >= n) return;
    int e0 = ptr[node], e1 = ptr[node + 1];
    float dv = dinv[node];
    int sub = lane / GS;   // edge sub-slot
    int cg = lane % GS;    // column group: cols [cg*8, cg*8+8)
    const _Float16* xp = (const _Float16*)xw + cg * 8;
    float acc[8];
#pragma unroll
    for (int i = 0; i < 8; i++) acc[i] = 0.f;

    for (int base = e0; base < e1; base += 64) {
        int cnt = min(e1 - base, 64);
        if (lane < cnt) smeta[wid][lane] = meta[base + lane];
        for (int j = 0; j < cnt; j += EPW) {
            int e = j + sub;
            bool valid = e < cnt;
            int s = smeta[wid][valid ? e : 0];
            half8 v = *(const half8*)(xp + (size_t)s * D);
            float msk = valid ? 1.f : 0.f;
#pragma unroll
            for (int i = 0; i < 8; i++) acc[i] = fmaf(msk, (float)v[i], acc[i]);
        }
    }
#pragma unroll
    for (int off = GS; off < 64; off <<= 1) {
#pragma unroll
        for (int i = 0; i < 8; i++) acc[i] += __shfl_xor(acc[i], off, 64);
    }
    if (lane < GS) {
        float4 bb0 = *(const float4*)(bias + cg * 8);
        float4 bb1 = *(const float4*)(bias + cg * 8 + 4);
        float r[8];
        r[0] = acc[0] * dv + bb0.x; r[1] = acc[1] * dv + bb0.y;
        r[2] = acc[2] * dv + bb0.z; r[3] = acc[3] * dv + bb0.w;
        r[4] = acc[4] * dv + bb1.x; r[5] = acc[5] * dv + bb1.y;
        r[6] = acc[6] * dv + bb1.z; r[7] = acc[7] * dv + bb1.w;
        if (RELU) {
#pragma unroll
            for (int i = 0; i < 8; i++) r[i] = fmaxf(r[i], 0.f);
        }
        if constexpr (sizeof(OT) == 2) {
            half8 h;
#pragma unroll
            for (int i = 0; i < 8; i++) h[i] = (_Float16)r[i];
            *(half8*)((_Float16*)out + (size_t)node * D + cg * 8) = h;
        } else {
            float* op = (float*)out + (size_t)node * D + cg * 8;
            *(float4*)op = make_float4(r[0], r[1], r[2], r[3]);
            *(float4*)(op + 4) = make_float4(r[4], r[5], r[6], r[7]);
        }
    }
}

extern "C" void kernel_launch(void* const* d_in, const int* in_sizes, int n_in,
                              void* d_out, int out_size, void* d_ws, size_t ws_size,
                              hipStream_t stream) {
    const float* x = (const float*)d_in[0];
    const int* ei = (const int*)d_in[1];
    const float* W1 = (const float*)d_in[2];
    const float* b1 = (const float*)d_in[3];
    const float* W2 = (const float*)d_in[4];
    const float* b2 = (const float*)d_in[5];
    const float* W3 = (const float*)d_in[6];
    const float* b3 = (const float*)d_in[7];
    float* out = (float*)d_out;
    int N = in_sizes[0] / 128;
    int E = in_sizes[1] / 2;
    const int* row = ei;
    const int* col = ei + E;
    int T = E + N;

    char* w = (char*)d_ws;
    size_t off = 0;
    auto alloc = [&](size_t bytes) -> void* {
        void* p = w + off;
        off = (off + bytes + 511) & ~(size_t)511;
        return p;
    };
    __half* bufH = (__half*)alloc((size_t)N * 128 * 2);   // xw (dinv-scaled, fp16)
    __half* bufA = (__half*)alloc((size_t)N * 128 * 2);   // hidden h (fp16 GEMM input)
    __half* Wt1 = (__half*)alloc(16384 * 2);
    __half* Wt2 = (__half*)alloc(16384 * 2);
    __half* Wt3 = (__half*)alloc(8192 * 2);
    int* deg = (int*)alloc((size_t)N * 4);
    float* dinv = (float*)alloc((size_t)N * 4);
    int* cptr = (int*)alloc((size_t)(N + 1) * 4);
    int* cur = (int*)alloc((size_t)N * 4);
    int* meta = (int*)alloc((size_t)T * 4);
    int* bsum = (int*)alloc(4096);

    int nb = (N + 1023) / 1024;
    wconv_k<<<160, 256, 0, stream>>>(W1, W2, W3, Wt1, Wt2, Wt3);
    deg_init_k<<<(N + 255) / 256, 256, 0, stream>>>(deg, N);
    deg_count_k<<<(E + 255) / 256, 256, 0, stream>>>(col, E, deg);
    dinv_k<<<(N + 255) / 256, 256, 0, stream>>>(deg, dinv, N);
    scan_p1<<<nb, 256, 0, stream>>>(deg, N, bsum);
    scan_p2<<<1, 256, 0, stream>>>(bsum, nb);
    scan_p3<<<nb, 256, 0, stream>>>(deg, N, bsum, cptr, cur);
    fill_k<<<8 * 256, 256, 0, stream>>>(row, col, E, N, cur, meta);

    int gb = (N + 127) / 128;
    int ab = (N + 3) / 4;
    gemm_mfma<float, 128><<<gb, 256, 0, stream>>>(x, Wt1, dinv, bufH, N);
    aggregate_k<128, true, __half><<<ab, 256, 0, stream>>>(bufH, cptr, meta, b1, dinv, bufA, N);
    gemm_mfma<__half, 128><<<gb, 256, 0, stream>>>(bufA, Wt2, dinv, bufH, N);
    aggregate_k<128, true, __half><<<ab, 256, 0, stream>>>(bufH, cptr, meta, b2, dinv, bufA, N);
    gemm_mfma<__half, 64><<<gb, 256, 0, stream>>>(bufA, Wt3, dinv, bufH, N);
    aggregate_k<64, false, float><<<ab, 256, 0, stream>>>(bufH, cptr, meta, b3, dinv, out, N);
}